// Round 5
// baseline (105.786 us; speedup 1.0000x reference)
//
#include <hip/hip_runtime.h>

// Problem constants (from reference)
#define Bsz  32
#define Nn   512
#define DIN  256
#define DSC  32
#define Cc   48
#define Hh   152
#define Ww   160
#define HW   (Hh * Ww)        // 24320
#define COUT (Cc + DSC)       // 80
#define TILE 256              // cells per gather tile; HW/TILE = 95 exactly
#define TPB  95               // gather tiles per batch
#define NGB  (Bsz * TPB)      // 3040 gather blocks
#define NCB  (Bsz * Cc * 2)   // 3072 copy blocks (half-plane each)
#define HP4  ((HW / 2) / 4)   // 3040 float4 per half-plane

// Native clang vector type — required by __builtin_nontemporal_*.
typedef float f4 __attribute__((ext_vector_type(4)));

// ---------------------------------------------------------------------------
// K1: proj = relu(emb @ W + b) * mask -> projws [B*N, DSC] (2 MB)
//     flat cell index per entity -> idxws [B*N]
// ---------------------------------------------------------------------------
__global__ __launch_bounds__(256) void proj_kernel(
    const float* __restrict__ emb, const float* __restrict__ mask,
    const int* __restrict__ loc, const float* __restrict__ Wp,
    const float* __restrict__ bp, float* __restrict__ projws,
    int* __restrict__ idxws) {

    __shared__ float Ws[DIN][DSC];        // 32 KB
    __shared__ float Es[32][DIN + 4];     // 32.5 KB, +4 pad for bank spread

    const int tid  = threadIdx.x;
    const int ent0 = blockIdx.x * 32;

    for (int i = tid; i < (DIN * DSC) / 4; i += 256)
        ((f4*)Ws)[i] = ((const f4*)Wp)[i];
    for (int i = tid; i < (32 * DIN) / 4; i += 256) {
        const int e  = i >> 6;
        const int k4 = i & 63;
        *(f4*)&Es[e][k4 * 4] = __builtin_nontemporal_load(
            (const f4*)(emb + (size_t)(ent0 + e) * DIN) + k4);
    }
    __syncthreads();

    const int g   = tid >> 3;             // entity within block
    const int dq  = (tid & 7) * 4;        // first of 4 output channels
    const int ent = ent0 + g;

    float ax = bp[dq + 0], ay = bp[dq + 1], az = bp[dq + 2], aw = bp[dq + 3];

    #pragma unroll 4
    for (int k = 0; k < DIN; k += 4) {
        const f4 ev = *(const f4*)&Es[g][k];
        const f4 w0 = *(const f4*)&Ws[k + 0][dq];
        const f4 w1 = *(const f4*)&Ws[k + 1][dq];
        const f4 w2 = *(const f4*)&Ws[k + 2][dq];
        const f4 w3 = *(const f4*)&Ws[k + 3][dq];
        ax = fmaf(ev.x, w0.x, fmaf(ev.y, w1.x, fmaf(ev.z, w2.x, fmaf(ev.w, w3.x, ax))));
        ay = fmaf(ev.x, w0.y, fmaf(ev.y, w1.y, fmaf(ev.z, w2.y, fmaf(ev.w, w3.y, ay))));
        az = fmaf(ev.x, w0.z, fmaf(ev.y, w1.z, fmaf(ev.z, w2.z, fmaf(ev.w, w3.z, az))));
        aw = fmaf(ev.x, w0.w, fmaf(ev.y, w1.w, fmaf(ev.z, w2.w, fmaf(ev.w, w3.w, aw))));
    }

    const float m = mask[ent];
    f4 r;
    r.x = fmaxf(ax, 0.f) * m;
    r.y = fmaxf(ay, 0.f) * m;
    r.z = fmaxf(az, 0.f) * m;
    r.w = fmaxf(aw, 0.f) * m;
    ((f4*)projws)[(size_t)ent * (DSC / 4) + (tid & 7)] = r;

    if ((tid & 7) == 0) {
        int y = loc[2 * ent + 0];
        int x = loc[2 * ent + 1];
        y = min(max(y, 0), Hh - 1);
        x = min(max(x, 0), Ww - 1);
        idxws[ent] = y * Ww + x;
    }
}

// ---------------------------------------------------------------------------
// K2: fused output assembly.
//  blocks [0, NCB):   copy half a spatial plane via NT load/store, 4-deep.
//  blocks [NCB,+NGB): gather one (b, 256-cell tile) x 32 channels in regs,
//                     NT stores out.
// ---------------------------------------------------------------------------
__global__ __launch_bounds__(256, 8) void fused_out_kernel(
    const float* __restrict__ spatial, const float* __restrict__ projws,
    const int* __restrict__ idxws, float* __restrict__ out) {

    __shared__ int   mlist[Nn];           // 2 KB: (r<<16)|entity
    __shared__ float pbuf[32][DSC];       // 4 KB: staged proj rows
    __shared__ int   mcount;

    const int bid = blockIdx.x;
    const int tid = threadIdx.x;

    if (bid < NCB) {                      // ---- copy half-plane, NT ----
        const int plane = bid >> 1;       // b*Cc + c
        const int half  = bid & 1;
        const int b = plane / Cc, c = plane % Cc;
        const f4* src = (const f4*)(spatial + (size_t)plane * HW) + half * HP4;
        f4*       dst = (f4*)(out + ((size_t)(b * COUT + c)) * HW) + half * HP4;
        int i = tid;
        #pragma unroll
        for (int r = 0; r < 2; ++r) {     // 2 rounds x 4-deep
            const f4 a0 = __builtin_nontemporal_load(src + i);
            const f4 a1 = __builtin_nontemporal_load(src + i + 256);
            const f4 a2 = __builtin_nontemporal_load(src + i + 512);
            const f4 a3 = __builtin_nontemporal_load(src + i + 768);
            __builtin_nontemporal_store(a0, dst + i);
            __builtin_nontemporal_store(a1, dst + i + 256);
            __builtin_nontemporal_store(a2, dst + i + 512);
            __builtin_nontemporal_store(a3, dst + i + 768);
            i += 1024;
        }
        {                                 // i = tid + 2048: 3-deep
            const f4 a0 = __builtin_nontemporal_load(src + i);
            const f4 a1 = __builtin_nontemporal_load(src + i + 256);
            const f4 a2 = __builtin_nontemporal_load(src + i + 512);
            __builtin_nontemporal_store(a0, dst + i);
            __builtin_nontemporal_store(a1, dst + i + 256);
            __builtin_nontemporal_store(a2, dst + i + 512);
            i += 768;                     // tid + 2816
        }
        if (i < HP4)                      // tail: 224 threads
            __builtin_nontemporal_store(__builtin_nontemporal_load(src + i), dst + i);
        return;
    }

    // ---- gather tile ----
    const int gid = bid - NCB;
    const int b   = gid / TPB;
    const int t0  = (gid % TPB) * TILE;

    if (tid == 0) mcount = 0;
    __syncthreads();
    {
        const int2 v = ((const int2*)(idxws + b * Nn))[tid];  // entities 2t, 2t+1
        const int r0 = v.x - t0, r1 = v.y - t0;
        if ((unsigned)r0 < (unsigned)TILE) {
            const int p = atomicAdd(&mcount, 1);
            mlist[p] = (r0 << 16) | (2 * tid);
        }
        if ((unsigned)r1 < (unsigned)TILE) {
            const int p = atomicAdd(&mcount, 1);
            mlist[p] = (r1 << 16) | (2 * tid + 1);
        }
    }
    __syncthreads();

    const int cg  = tid & 63;             // cells 4cg .. 4cg+3
    const int ch0 = (tid >> 6) * 8;       // channels ch0 .. ch0+7
    f4 acc[8];
    #pragma unroll
    for (int j = 0; j < 8; ++j) acc[j] = (f4)(0.f);

    const int M = mcount;
    for (int m0 = 0; m0 < M; m0 += 32) {
        const int nm = min(32, M - m0);
        if (tid < nm * 8) {
            const int m   = tid >> 3;
            const int ent = mlist[m0 + m] & 0xFFFF;
            ((f4*)pbuf[m])[tid & 7] =
                ((const f4*)(projws + ((size_t)b * Nn + ent) * DSC))[tid & 7];
        }
        __syncthreads();
        for (int mm = 0; mm < nm; ++mm) {
            const int rk = mlist[m0 + mm] >> 16;
            if ((rk >> 2) == cg) {
                const f4 f0 = *(const f4*)&pbuf[mm][ch0];
                const f4 f1 = *(const f4*)&pbuf[mm][ch0 + 4];
                switch (rk & 3) {
                case 0:
                    acc[0].x += f0.x; acc[1].x += f0.y; acc[2].x += f0.z; acc[3].x += f0.w;
                    acc[4].x += f1.x; acc[5].x += f1.y; acc[6].x += f1.z; acc[7].x += f1.w;
                    break;
                case 1:
                    acc[0].y += f0.x; acc[1].y += f0.y; acc[2].y += f0.z; acc[3].y += f0.w;
                    acc[4].y += f1.x; acc[5].y += f1.y; acc[6].y += f1.z; acc[7].y += f1.w;
                    break;
                case 2:
                    acc[0].z += f0.x; acc[1].z += f0.y; acc[2].z += f0.z; acc[3].z += f0.w;
                    acc[4].z += f1.x; acc[5].z += f1.y; acc[6].z += f1.z; acc[7].z += f1.w;
                    break;
                default:
                    acc[0].w += f0.x; acc[1].w += f0.y; acc[2].w += f0.z; acc[3].w += f0.w;
                    acc[4].w += f1.x; acc[5].w += f1.y; acc[6].w += f1.z; acc[7].w += f1.w;
                    break;
                }
            }
        }
        __syncthreads();
    }

    float* obase = out + ((size_t)b * COUT + Cc) * HW + t0 + 4 * cg;
    #pragma unroll
    for (int j = 0; j < 8; ++j)
        __builtin_nontemporal_store(acc[j], (f4*)(obase + (size_t)(ch0 + j) * HW));
}

// ---------------------------------------------------------------------------
// Fallback path (only if ws_size too small): R1 design.
// ---------------------------------------------------------------------------
__global__ __launch_bounds__(256) void init_out_kernel(
    const float* __restrict__ spatial, float* __restrict__ out) {
    const int plane = blockIdx.x;
    const int b = plane / COUT;
    const int c = plane % COUT;
    f4* dst = (f4*)(out + (size_t)plane * HW);
    if (c < Cc) {
        const f4* src = (const f4*)(spatial + ((size_t)b * Cc + c) * HW);
        for (int i = threadIdx.x; i < HW / 4; i += blockDim.x) dst[i] = src[i];
    } else {
        for (int i = threadIdx.x; i < HW / 4; i += blockDim.x) dst[i] = (f4)(0.f);
    }
}

__global__ __launch_bounds__(256) void scatter_kernel(
    const float* __restrict__ emb, const float* __restrict__ mask,
    const int* __restrict__ loc, const float* __restrict__ Wp,
    const float* __restrict__ bp, float* __restrict__ out) {

    __shared__ float Ws[DIN][DSC];
    __shared__ float Es[32][DIN + 4];

    const int tid  = threadIdx.x;
    const int ent0 = blockIdx.x * 32;

    for (int i = tid; i < (DIN * DSC) / 4; i += 256)
        ((f4*)Ws)[i] = ((const f4*)Wp)[i];
    for (int i = tid; i < (32 * DIN) / 4; i += 256) {
        const int e  = i >> 6;
        const int k4 = i & 63;
        *(f4*)&Es[e][k4 * 4] =
            ((const f4*)(emb + (size_t)(ent0 + e) * DIN))[k4];
    }
    __syncthreads();

    const int g   = tid >> 3;
    const int dq  = (tid & 7) * 4;
    const int ent = ent0 + g;
    const int b   = ent >> 9;

    float ax = bp[dq + 0], ay = bp[dq + 1], az = bp[dq + 2], aw = bp[dq + 3];

    #pragma unroll 4
    for (int k = 0; k < DIN; k += 4) {
        const f4 ev = *(const f4*)&Es[g][k];
        const f4 w0 = *(const f4*)&Ws[k + 0][dq];
        const f4 w1 = *(const f4*)&Ws[k + 1][dq];
        const f4 w2 = *(const f4*)&Ws[k + 2][dq];
        const f4 w3 = *(const f4*)&Ws[k + 3][dq];
        ax = fmaf(ev.x, w0.x, fmaf(ev.y, w1.x, fmaf(ev.z, w2.x, fmaf(ev.w, w3.x, ax))));
        ay = fmaf(ev.x, w0.y, fmaf(ev.y, w1.y, fmaf(ev.z, w2.y, fmaf(ev.w, w3.y, ay))));
        az = fmaf(ev.x, w0.z, fmaf(ev.y, w1.z, fmaf(ev.z, w2.z, fmaf(ev.w, w3.z, az))));
        aw = fmaf(ev.x, w0.w, fmaf(ev.y, w1.w, fmaf(ev.z, w2.w, fmaf(ev.w, w3.w, aw))));
    }

    const float m = mask[ent];
    int y = loc[2 * ent + 0];
    int x = loc[2 * ent + 1];
    y = min(max(y, 0), Hh - 1);
    x = min(max(x, 0), Ww - 1);

    float* dst = out + ((size_t)b * COUT + Cc) * HW + (size_t)y * Ww + x;
    float v[4] = { ax, ay, az, aw };
    #pragma unroll
    for (int j = 0; j < 4; ++j) {
        const float r = fmaxf(v[j], 0.f) * m;
        if (r != 0.f)
            atomicAdd(dst + (size_t)(dq + j) * HW, r);
    }
}

// ---------------------------------------------------------------------------
extern "C" void kernel_launch(void* const* d_in, const int* in_sizes, int n_in,
                              void* d_out, int out_size, void* d_ws, size_t ws_size,
                              hipStream_t stream) {
    const float* spatial = (const float*)d_in[0];  // [B, C, H, W]
    const float* emb     = (const float*)d_in[1];  // [B, N, DIN]
    const float* mask    = (const float*)d_in[2];  // [B, N]
    const int*   loc     = (const int*)d_in[3];    // [B, N, 2]
    const float* Wp      = (const float*)d_in[4];  // [DIN, DSC]
    const float* bp      = (const float*)d_in[5];  // [DSC]
    float* out = (float*)d_out;                    // [B, COUT, H, W]

    const size_t need = (size_t)Bsz * Nn * DSC * sizeof(float)
                      + (size_t)Bsz * Nn * sizeof(int);
    if (ws_size >= need) {
        float* projws = (float*)d_ws;
        int*   idxws  = (int*)((char*)d_ws + (size_t)Bsz * Nn * DSC * sizeof(float));
        proj_kernel<<<(Bsz * Nn) / 32, 256, 0, stream>>>(emb, mask, loc, Wp, bp,
                                                         projws, idxws);
        fused_out_kernel<<<NCB + NGB, 256, 0, stream>>>(spatial, projws, idxws, out);
    } else {
        init_out_kernel<<<Bsz * COUT, 256, 0, stream>>>(spatial, out);
        scatter_kernel<<<(Bsz * Nn) / 32, 256, 0, stream>>>(emb, mask, loc, Wp, bp, out);
    }
}

// Round 6
// 89.576 us; speedup vs baseline: 1.1810x; 1.1810x over previous
//
#include <hip/hip_runtime.h>

// Problem constants (from reference)
#define Bsz  32
#define Nn   512
#define DIN  256
#define DSC  32
#define Cc   48
#define Hh   152
#define Ww   160
#define HW   (Hh * Ww)        // 24320
#define COUT (Cc + DSC)       // 80
#define HALF (HW / 2)         // 12160 cells per half-plane
#define HP4  (HALF / 4)       // 3040 float4 per half-plane

// Copy-kernel geometry: linear over spatial (one contiguous 149 MB stream).
#define CP_N4     (Bsz * Cc * (HW / 4))   // 9,338,880 float4 to copy
#define CP_GRID   2048
#define CP_THREAD 256
#define CP_STRIDE (CP_GRID * CP_THREAD)   // 524,288 f4 = 8 MB sliding window
#define CP_FULL   (CP_N4 / CP_STRIDE)     // 17 full rounds
#define CP_TAIL   (CP_N4 - CP_FULL * CP_STRIDE)  // 425,984
#define SLAB4     (Cc * (HW / 4))         // 291,840 f4 per batch copy-slab

// Native clang vector type — required by __builtin_nontemporal_*.
typedef float f4 __attribute__((ext_vector_type(4)));

// ---------------------------------------------------------------------------
// K1: proj = relu(emb @ W + b) * mask -> projws [B*N, DSC] (2 MB, L2-resident)
//     flat cell index per entity -> idxws [B*N]
// ---------------------------------------------------------------------------
__global__ __launch_bounds__(256) void proj_kernel(
    const float* __restrict__ emb, const float* __restrict__ mask,
    const int* __restrict__ loc, const float* __restrict__ Wp,
    const float* __restrict__ bp, float* __restrict__ projws,
    int* __restrict__ idxws) {

    __shared__ float Ws[DIN][DSC];        // 32 KB
    __shared__ float Es[32][DIN + 4];     // 32.5 KB, +4 pad for bank spread

    const int tid  = threadIdx.x;
    const int ent0 = blockIdx.x * 32;

    for (int i = tid; i < (DIN * DSC) / 4; i += 256)
        ((f4*)Ws)[i] = ((const f4*)Wp)[i];
    for (int i = tid; i < (32 * DIN) / 4; i += 256) {
        const int e  = i >> 6;
        const int k4 = i & 63;
        *(f4*)&Es[e][k4 * 4] = __builtin_nontemporal_load(
            (const f4*)(emb + (size_t)(ent0 + e) * DIN) + k4);
    }
    __syncthreads();

    const int g   = tid >> 3;             // entity within block
    const int dq  = (tid & 7) * 4;        // first of 4 output channels
    const int ent = ent0 + g;

    float ax = bp[dq + 0], ay = bp[dq + 1], az = bp[dq + 2], aw = bp[dq + 3];

    #pragma unroll 4
    for (int k = 0; k < DIN; k += 4) {
        const f4 ev = *(const f4*)&Es[g][k];
        const f4 w0 = *(const f4*)&Ws[k + 0][dq];
        const f4 w1 = *(const f4*)&Ws[k + 1][dq];
        const f4 w2 = *(const f4*)&Ws[k + 2][dq];
        const f4 w3 = *(const f4*)&Ws[k + 3][dq];
        ax = fmaf(ev.x, w0.x, fmaf(ev.y, w1.x, fmaf(ev.z, w2.x, fmaf(ev.w, w3.x, ax))));
        ay = fmaf(ev.x, w0.y, fmaf(ev.y, w1.y, fmaf(ev.z, w2.y, fmaf(ev.w, w3.y, ay))));
        az = fmaf(ev.x, w0.z, fmaf(ev.y, w1.z, fmaf(ev.z, w2.z, fmaf(ev.w, w3.z, az))));
        aw = fmaf(ev.x, w0.w, fmaf(ev.y, w1.w, fmaf(ev.z, w2.w, fmaf(ev.w, w3.w, aw))));
    }

    const float m = mask[ent];
    f4 r;
    r.x = fmaxf(ax, 0.f) * m;
    r.y = fmaxf(ay, 0.f) * m;
    r.z = fmaxf(az, 0.f) * m;
    r.w = fmaxf(aw, 0.f) * m;
    ((f4*)projws)[(size_t)ent * (DSC / 4) + (tid & 7)] = r;

    if ((tid & 7) == 0) {
        int y = loc[2 * ent + 0];
        int x = loc[2 * ent + 1];
        y = min(max(y, 0), Hh - 1);
        x = min(max(x, 0), Ww - 1);
        idxws[ent] = y * Ww + x;
    }
}

// ---------------------------------------------------------------------------
// K2: copy spatial -> out[:, 0:48] as ONE grid-stride linear stream.
// src index i is linear over spatial; dst = i + b*(COUT-Cc)*HW/4 where
// b = i / SLAB4 (u32 const-div -> magic mul). All 2048 blocks co-resident:
// the whole grid walks an 8 MB contiguous window that slides forward —
// same access shape as the 6.3 TB/s reference copy.
// ---------------------------------------------------------------------------
__global__ __launch_bounds__(CP_THREAD) void copy_kernel(
    const float* __restrict__ spatial, float* __restrict__ out) {
    const f4* __restrict__ src = (const f4*)spatial;
    f4* __restrict__       dst = (f4*)out;

    unsigned i = blockIdx.x * CP_THREAD + threadIdx.x;
    #pragma unroll 1
    for (int k = 0; k < CP_FULL; ++k) {
        const unsigned b = i / (unsigned)SLAB4;
        __builtin_nontemporal_store(__builtin_nontemporal_load(src + i),
                                    dst + i + b * (unsigned)((COUT - Cc) * (HW / 4)));
        i += CP_STRIDE;
    }
    if (i < (unsigned)CP_N4) {
        const unsigned b = i / (unsigned)SLAB4;
        __builtin_nontemporal_store(__builtin_nontemporal_load(src + i),
                                    dst + i + b * (unsigned)((COUT - Cc) * (HW / 4)));
    }
}

// ---------------------------------------------------------------------------
// K3: gather. Block = (b, scatter-channel c, half-plane). Zero a 48.6 KB LDS
// accumulator, scan the batch's 512 entity cells (2/thread, coalesced int2),
// LDS-atomicAdd the ~256 in-range contributions (proj scalar from L2-resident
// projws; zero values skipped — exact), then dump the half-plane as one
// contiguous NT stream. Blocks ordered by dst address.
// ---------------------------------------------------------------------------
__global__ __launch_bounds__(256) void gather_kernel(
    const float* __restrict__ projws, const int* __restrict__ idxws,
    float* __restrict__ out) {

    __shared__ float facc[HALF];          // 48,640 B

    const int g    = blockIdx.x;          // 0 .. Bsz*DSC*2-1, dst-address order
    const int b    = g >> 6;
    const int c    = (g >> 1) & 31;
    const int lo   = (g & 1) * HALF;
    const int tid  = threadIdx.x;

    for (int i = tid; i < HP4; i += 256) ((f4*)facc)[i] = (f4)(0.f);
    __syncthreads();

    const int2 v = ((const int2*)(idxws + b * Nn))[tid];  // entities 2t, 2t+1
    {
        const int r0 = v.x - lo;
        if ((unsigned)r0 < (unsigned)HALF) {
            const float p = projws[((size_t)b * Nn + 2 * tid) * DSC + c];
            if (p != 0.f) atomicAdd(&facc[r0], p);
        }
        const int r1 = v.y - lo;
        if ((unsigned)r1 < (unsigned)HALF) {
            const float p = projws[((size_t)b * Nn + 2 * tid + 1) * DSC + c];
            if (p != 0.f) atomicAdd(&facc[r1], p);
        }
    }
    __syncthreads();

    f4* obase = (f4*)(out + ((size_t)(b * COUT + Cc + c)) * HW + lo);
    for (int i = tid; i < HP4; i += 256)
        __builtin_nontemporal_store(((const f4*)facc)[i], obase + i);
}

// ---------------------------------------------------------------------------
// Fallback path (only if ws_size too small): R1 design.
// ---------------------------------------------------------------------------
__global__ __launch_bounds__(256) void init_out_kernel(
    const float* __restrict__ spatial, float* __restrict__ out) {
    const int plane = blockIdx.x;
    const int b = plane / COUT;
    const int c = plane % COUT;
    f4* dst = (f4*)(out + (size_t)plane * HW);
    if (c < Cc) {
        const f4* src = (const f4*)(spatial + ((size_t)b * Cc + c) * HW);
        for (int i = threadIdx.x; i < HW / 4; i += blockDim.x) dst[i] = src[i];
    } else {
        for (int i = threadIdx.x; i < HW / 4; i += blockDim.x) dst[i] = (f4)(0.f);
    }
}

__global__ __launch_bounds__(256) void scatter_kernel(
    const float* __restrict__ emb, const float* __restrict__ mask,
    const int* __restrict__ loc, const float* __restrict__ Wp,
    const float* __restrict__ bp, float* __restrict__ out) {

    __shared__ float Ws[DIN][DSC];
    __shared__ float Es[32][DIN + 4];

    const int tid  = threadIdx.x;
    const int ent0 = blockIdx.x * 32;

    for (int i = tid; i < (DIN * DSC) / 4; i += 256)
        ((f4*)Ws)[i] = ((const f4*)Wp)[i];
    for (int i = tid; i < (32 * DIN) / 4; i += 256) {
        const int e  = i >> 6;
        const int k4 = i & 63;
        *(f4*)&Es[e][k4 * 4] =
            ((const f4*)(emb + (size_t)(ent0 + e) * DIN))[k4];
    }
    __syncthreads();

    const int g   = tid >> 3;
    const int dq  = (tid & 7) * 4;
    const int ent = ent0 + g;
    const int b   = ent >> 9;

    float ax = bp[dq + 0], ay = bp[dq + 1], az = bp[dq + 2], aw = bp[dq + 3];

    #pragma unroll 4
    for (int k = 0; k < DIN; k += 4) {
        const f4 ev = *(const f4*)&Es[g][k];
        const f4 w0 = *(const f4*)&Ws[k + 0][dq];
        const f4 w1 = *(const f4*)&Ws[k + 1][dq];
        const f4 w2 = *(const f4*)&Ws[k + 2][dq];
        const f4 w3 = *(const f4*)&Ws[k + 3][dq];
        ax = fmaf(ev.x, w0.x, fmaf(ev.y, w1.x, fmaf(ev.z, w2.x, fmaf(ev.w, w3.x, ax))));
        ay = fmaf(ev.x, w0.y, fmaf(ev.y, w1.y, fmaf(ev.z, w2.y, fmaf(ev.w, w3.y, ay))));
        az = fmaf(ev.x, w0.z, fmaf(ev.y, w1.z, fmaf(ev.z, w2.z, fmaf(ev.w, w3.z, az))));
        aw = fmaf(ev.x, w0.w, fmaf(ev.y, w1.w, fmaf(ev.z, w2.w, fmaf(ev.w, w3.w, aw))));
    }

    const float m = mask[ent];
    int y = loc[2 * ent + 0];
    int x = loc[2 * ent + 1];
    y = min(max(y, 0), Hh - 1);
    x = min(max(x, 0), Ww - 1);

    float* dst = out + ((size_t)b * COUT + Cc) * HW + (size_t)y * Ww + x;
    float v[4] = { ax, ay, az, aw };
    #pragma unroll
    for (int j = 0; j < 4; ++j) {
        const float r = fmaxf(v[j], 0.f) * m;
        if (r != 0.f)
            atomicAdd(dst + (size_t)(dq + j) * HW, r);
    }
}

// ---------------------------------------------------------------------------
extern "C" void kernel_launch(void* const* d_in, const int* in_sizes, int n_in,
                              void* d_out, int out_size, void* d_ws, size_t ws_size,
                              hipStream_t stream) {
    const float* spatial = (const float*)d_in[0];  // [B, C, H, W]
    const float* emb     = (const float*)d_in[1];  // [B, N, DIN]
    const float* mask    = (const float*)d_in[2];  // [B, N]
    const int*   loc     = (const int*)d_in[3];    // [B, N, 2]
    const float* Wp      = (const float*)d_in[4];  // [DIN, DSC]
    const float* bp      = (const float*)d_in[5];  // [DSC]
    float* out = (float*)d_out;                    // [B, COUT, H, W]

    const size_t need = (size_t)Bsz * Nn * DSC * sizeof(float)
                      + (size_t)Bsz * Nn * sizeof(int);
    if (ws_size >= need) {
        float* projws = (float*)d_ws;
        int*   idxws  = (int*)((char*)d_ws + (size_t)Bsz * Nn * DSC * sizeof(float));
        proj_kernel<<<(Bsz * Nn) / 32, 256, 0, stream>>>(emb, mask, loc, Wp, bp,
                                                         projws, idxws);
        copy_kernel<<<CP_GRID, CP_THREAD, 0, stream>>>(spatial, out);
        gather_kernel<<<Bsz * DSC * 2, 256, 0, stream>>>(projws, idxws, out);
    } else {
        init_out_kernel<<<Bsz * COUT, 256, 0, stream>>>(spatial, out);
        scatter_kernel<<<(Bsz * Nn) / 32, 256, 0, stream>>>(emb, mask, loc, Wp, bp, out);
    }
}

// Round 7
// 80.757 us; speedup vs baseline: 1.3099x; 1.1092x over previous
//
#include <hip/hip_runtime.h>

// Problem constants (from reference)
#define Bsz  32
#define Nn   512
#define DIN  256
#define DSC  32
#define Cc   48
#define Hh   152
#define Ww   160
#define HW   (Hh * Ww)        // 24320
#define COUT (Cc + DSC)       // 80
#define HALF (HW / 2)         // 12160 cells per half-plane
#define HP4  (HALF / 4)       // 3040 float4 per half-plane

// Copy geometry: linear over spatial (one contiguous 149 MB stream).
#define CP_N4     (Bsz * Cc * (HW / 4))   // 9,338,880 float4 to copy
#define CP_GRID   2048
#define CP_THREAD 256
#define CP_STRIDE (CP_GRID * CP_THREAD)   // 524,288 f4 = 8 MB sliding window
#define CP_FULL   (CP_N4 / CP_STRIDE)     // 17 full rounds
#define SLAB4     (Cc * (HW / 4))         // 291,840 f4 per batch copy-slab
#define PR_GRID   ((Bsz * Nn) / 32)       // 512 proj blocks

// Native clang vector type — required by __builtin_nontemporal_*.
typedef float f4 __attribute__((ext_vector_type(4)));

// ---------------------------------------------------------------------------
// Kernel A: copy + proj fused in one launch.
//  blocks [0, CP_GRID):  grid-stride sliding-window copy spatial -> out[:,0:48]
//                        (NT load/store; whole grid walks one contiguous
//                        8 MB window that slides forward — 6.3 TB/s shape).
//  blocks [CP_GRID, +PR_GRID): proj = relu(emb @ W + b) * mask -> projws,
//                        flat cell index -> idxws. W staged in 32 KB LDS
//                        (5 blocks/CU keeps copy at ~20 waves/CU); emb rows
//                        read direct from global (8 same-address lanes
//                        coalesce; row L1-resident across the k-loop).
// ---------------------------------------------------------------------------
__global__ __launch_bounds__(CP_THREAD, 4) void copy_proj_kernel(
    const float* __restrict__ spatial, const float* __restrict__ emb,
    const float* __restrict__ mask, const int* __restrict__ loc,
    const float* __restrict__ Wp, const float* __restrict__ bp,
    float* __restrict__ out, float* __restrict__ projws,
    int* __restrict__ idxws) {

    __shared__ float Ws[DIN][DSC];        // 32 KB (proj blocks only)

    const int bid = blockIdx.x;
    const int tid = threadIdx.x;

    if (bid < CP_GRID) {                  // ---- sliding-window copy ----
        const f4* __restrict__ src = (const f4*)spatial;
        f4* __restrict__       dst = (f4*)out;
        unsigned i = bid * CP_THREAD + tid;
        #pragma unroll 1
        for (int k = 0; k < CP_FULL; ++k) {
            const unsigned b = i / (unsigned)SLAB4;
            __builtin_nontemporal_store(__builtin_nontemporal_load(src + i),
                dst + i + b * (unsigned)((COUT - Cc) * (HW / 4)));
            i += CP_STRIDE;
        }
        if (i < (unsigned)CP_N4) {
            const unsigned b = i / (unsigned)SLAB4;
            __builtin_nontemporal_store(__builtin_nontemporal_load(src + i),
                dst + i + b * (unsigned)((COUT - Cc) * (HW / 4)));
        }
        return;
    }

    // ---- proj ----
    const int ent0 = (bid - CP_GRID) * 32;

    for (int i = tid; i < (DIN * DSC) / 4; i += 256)
        ((f4*)Ws)[i] = ((const f4*)Wp)[i];
    __syncthreads();

    const int g   = tid >> 3;             // entity within block
    const int dq  = (tid & 7) * 4;        // first of 4 output channels
    const int ent = ent0 + g;

    const f4* __restrict__ erow = (const f4*)(emb + (size_t)ent * DIN);

    float ax = bp[dq + 0], ay = bp[dq + 1], az = bp[dq + 2], aw = bp[dq + 3];

    #pragma unroll 4
    for (int k4 = 0; k4 < DIN / 4; ++k4) {
        const f4 ev = erow[k4];
        const int k = k4 * 4;
        const f4 w0 = *(const f4*)&Ws[k + 0][dq];
        const f4 w1 = *(const f4*)&Ws[k + 1][dq];
        const f4 w2 = *(const f4*)&Ws[k + 2][dq];
        const f4 w3 = *(const f4*)&Ws[k + 3][dq];
        ax = fmaf(ev.x, w0.x, fmaf(ev.y, w1.x, fmaf(ev.z, w2.x, fmaf(ev.w, w3.x, ax))));
        ay = fmaf(ev.x, w0.y, fmaf(ev.y, w1.y, fmaf(ev.z, w2.y, fmaf(ev.w, w3.y, ay))));
        az = fmaf(ev.x, w0.z, fmaf(ev.y, w1.z, fmaf(ev.z, w2.z, fmaf(ev.w, w3.z, az))));
        aw = fmaf(ev.x, w0.w, fmaf(ev.y, w1.w, fmaf(ev.z, w2.w, fmaf(ev.w, w3.w, aw))));
    }

    const float m = mask[ent];
    f4 r;
    r.x = fmaxf(ax, 0.f) * m;
    r.y = fmaxf(ay, 0.f) * m;
    r.z = fmaxf(az, 0.f) * m;
    r.w = fmaxf(aw, 0.f) * m;
    ((f4*)projws)[(size_t)ent * (DSC / 4) + (tid & 7)] = r;

    if ((tid & 7) == 0) {
        int y = loc[2 * ent + 0];
        int x = loc[2 * ent + 1];
        y = min(max(y, 0), Hh - 1);
        x = min(max(x, 0), Ww - 1);
        idxws[ent] = y * Ww + x;
    }
}

// ---------------------------------------------------------------------------
// Kernel B: gather. Block = (b, scatter-channel c, half-plane). Zero a
// 48.6 KB LDS accumulator, scan the batch's 512 entity cells (2/thread),
// LDS-atomicAdd in-range contributions (proj from L2-resident projws; zero
// values skipped — exact), then dump as one contiguous NT stream. Blocks
// ordered by dst address.
// ---------------------------------------------------------------------------
__global__ __launch_bounds__(256) void gather_kernel(
    const float* __restrict__ projws, const int* __restrict__ idxws,
    float* __restrict__ out) {

    __shared__ float facc[HALF];          // 48,640 B

    const int g    = blockIdx.x;          // 0 .. Bsz*DSC*2-1, dst-address order
    const int b    = g >> 6;
    const int c    = (g >> 1) & 31;
    const int lo   = (g & 1) * HALF;
    const int tid  = threadIdx.x;

    for (int i = tid; i < HP4; i += 256) ((f4*)facc)[i] = (f4)(0.f);
    __syncthreads();

    const int2 v = ((const int2*)(idxws + b * Nn))[tid];  // entities 2t, 2t+1
    {
        const int r0 = v.x - lo;
        if ((unsigned)r0 < (unsigned)HALF) {
            const float p = projws[((size_t)b * Nn + 2 * tid) * DSC + c];
            if (p != 0.f) atomicAdd(&facc[r0], p);
        }
        const int r1 = v.y - lo;
        if ((unsigned)r1 < (unsigned)HALF) {
            const float p = projws[((size_t)b * Nn + 2 * tid + 1) * DSC + c];
            if (p != 0.f) atomicAdd(&facc[r1], p);
        }
    }
    __syncthreads();

    f4* obase = (f4*)(out + ((size_t)(b * COUT + Cc + c)) * HW + lo);
    for (int i = tid; i < HP4; i += 256)
        __builtin_nontemporal_store(((const f4*)facc)[i], obase + i);
}

// ---------------------------------------------------------------------------
// Fallback path (only if ws_size too small): R1 design.
// ---------------------------------------------------------------------------
__global__ __launch_bounds__(256) void init_out_kernel(
    const float* __restrict__ spatial, float* __restrict__ out) {
    const int plane = blockIdx.x;
    const int b = plane / COUT;
    const int c = plane % COUT;
    f4* dst = (f4*)(out + (size_t)plane * HW);
    if (c < Cc) {
        const f4* src = (const f4*)(spatial + ((size_t)b * Cc + c) * HW);
        for (int i = threadIdx.x; i < HW / 4; i += blockDim.x) dst[i] = src[i];
    } else {
        for (int i = threadIdx.x; i < HW / 4; i += blockDim.x) dst[i] = (f4)(0.f);
    }
}

__global__ __launch_bounds__(256) void scatter_kernel(
    const float* __restrict__ emb, const float* __restrict__ mask,
    const int* __restrict__ loc, const float* __restrict__ Wp,
    const float* __restrict__ bp, float* __restrict__ out) {

    __shared__ float Ws[DIN][DSC];
    __shared__ float Es[32][DIN + 4];

    const int tid  = threadIdx.x;
    const int ent0 = blockIdx.x * 32;

    for (int i = tid; i < (DIN * DSC) / 4; i += 256)
        ((f4*)Ws)[i] = ((const f4*)Wp)[i];
    for (int i = tid; i < (32 * DIN) / 4; i += 256) {
        const int e  = i >> 6;
        const int k4 = i & 63;
        *(f4*)&Es[e][k4 * 4] =
            ((const f4*)(emb + (size_t)(ent0 + e) * DIN))[k4];
    }
    __syncthreads();

    const int g   = tid >> 3;
    const int dq  = (tid & 7) * 4;
    const int ent = ent0 + g;
    const int b   = ent >> 9;

    float ax = bp[dq + 0], ay = bp[dq + 1], az = bp[dq + 2], aw = bp[dq + 3];

    #pragma unroll 4
    for (int k = 0; k < DIN; k += 4) {
        const f4 ev = *(const f4*)&Es[g][k];
        const f4 w0 = *(const f4*)&Ws[k + 0][dq];
        const f4 w1 = *(const f4*)&Ws[k + 1][dq];
        const f4 w2 = *(const f4*)&Ws[k + 2][dq];
        const f4 w3 = *(const f4*)&Ws[k + 3][dq];
        ax = fmaf(ev.x, w0.x, fmaf(ev.y, w1.x, fmaf(ev.z, w2.x, fmaf(ev.w, w3.x, ax))));
        ay = fmaf(ev.x, w0.y, fmaf(ev.y, w1.y, fmaf(ev.z, w2.y, fmaf(ev.w, w3.y, ay))));
        az = fmaf(ev.x, w0.z, fmaf(ev.y, w1.z, fmaf(ev.z, w2.z, fmaf(ev.w, w3.z, az))));
        aw = fmaf(ev.x, w0.w, fmaf(ev.y, w1.w, fmaf(ev.z, w2.w, fmaf(ev.w, w3.w, aw))));
    }

    const float m = mask[ent];
    int y = loc[2 * ent + 0];
    int x = loc[2 * ent + 1];
    y = min(max(y, 0), Hh - 1);
    x = min(max(x, 0), Ww - 1);

    float* dst = out + ((size_t)b * COUT + Cc) * HW + (size_t)y * Ww + x;
    float v[4] = { ax, ay, az, aw };
    #pragma unroll
    for (int j = 0; j < 4; ++j) {
        const float r = fmaxf(v[j], 0.f) * m;
        if (r != 0.f)
            atomicAdd(dst + (size_t)(dq + j) * HW, r);
    }
}

// ---------------------------------------------------------------------------
extern "C" void kernel_launch(void* const* d_in, const int* in_sizes, int n_in,
                              void* d_out, int out_size, void* d_ws, size_t ws_size,
                              hipStream_t stream) {
    const float* spatial = (const float*)d_in[0];  // [B, C, H, W]
    const float* emb     = (const float*)d_in[1];  // [B, N, DIN]
    const float* mask    = (const float*)d_in[2];  // [B, N]
    const int*   loc     = (const int*)d_in[3];    // [B, N, 2]
    const float* Wp      = (const float*)d_in[4];  // [DIN, DSC]
    const float* bp      = (const float*)d_in[5];  // [DSC]
    float* out = (float*)d_out;                    // [B, COUT, H, W]

    const size_t need = (size_t)Bsz * Nn * DSC * sizeof(float)
                      + (size_t)Bsz * Nn * sizeof(int);
    if (ws_size >= need) {
        float* projws = (float*)d_ws;
        int*   idxws  = (int*)((char*)d_ws + (size_t)Bsz * Nn * DSC * sizeof(float));
        copy_proj_kernel<<<CP_GRID + PR_GRID, CP_THREAD, 0, stream>>>(
            spatial, emb, mask, loc, Wp, bp, out, projws, idxws);
        gather_kernel<<<Bsz * DSC * 2, 256, 0, stream>>>(projws, idxws, out);
    } else {
        init_out_kernel<<<Bsz * COUT, 256, 0, stream>>>(spatial, out);
        scatter_kernel<<<(Bsz * Nn) / 32, 256, 0, stream>>>(emb, mask, loc, Wp, bp, out);
    }
}

// Round 8
// 80.289 us; speedup vs baseline: 1.3176x; 1.0058x over previous
//
#include <hip/hip_runtime.h>

// Problem constants (from reference)
#define Bsz  32
#define Nn   512
#define DIN  256
#define DSC  32
#define Cc   48
#define Hh   152
#define Ww   160
#define HW   (Hh * Ww)        // 24320
#define COUT (Cc + DSC)       // 80
#define HALF (HW / 2)         // 12160 cells per half-plane
#define HP4  (HALF / 4)       // 3040 float4 per half-plane

// Copy geometry: linear over spatial (one contiguous 149 MB stream).
#define CP_N4     (Bsz * Cc * (HW / 4))   // 9,338,880 float4 to copy
#define CP_GRID   2048
#define CP_THREAD 256
#define CP_STRIDE (CP_GRID * CP_THREAD)   // 524,288 f4 = 8 MB sliding window
#define SLAB4     (Cc * (HW / 4))         // 291,840 f4 per batch copy-slab
#define SC4       ((COUT - Cc) * (HW / 4))// 194,560 f4 dst slab shift per batch
#define PR_GRID   ((Bsz * Nn) / 32)       // 512 proj blocks

// Native clang vector type — required by __builtin_nontemporal_*.
typedef float f4 __attribute__((ext_vector_type(4)));

// ---------------------------------------------------------------------------
// Kernel A: proj + copy fused. PROJ BLOCKS FIRST (bid 0..511) so they
// schedule at launch and their ~10 us hides under the copy ramp.
//  blocks [0, PR_GRID):          proj = relu(emb @ W + b) * mask -> projws,
//                                cell index -> idxws. W staged in 32 KB LDS.
//  blocks [PR_GRID, +CP_GRID):   grid-stride sliding-window copy
//                                spatial -> out[:,0:48], NT, UNROLL x4:
//                                4 loads batched then 4 stores batched ->
//                                4 memory ops in flight per wave.
// ---------------------------------------------------------------------------
__global__ __launch_bounds__(CP_THREAD, 4) void proj_copy_kernel(
    const float* __restrict__ spatial, const float* __restrict__ emb,
    const float* __restrict__ mask, const int* __restrict__ loc,
    const float* __restrict__ Wp, const float* __restrict__ bp,
    float* __restrict__ out, float* __restrict__ projws,
    int* __restrict__ idxws) {

    __shared__ float Ws[DIN][DSC];        // 32 KB (proj blocks only)

    const int bid = blockIdx.x;
    const int tid = threadIdx.x;

    if (bid >= PR_GRID) {                 // ---- sliding-window copy ----
        const f4* __restrict__ src = (const f4*)spatial;
        f4* __restrict__       dst = (f4*)out;
        unsigned i = (bid - PR_GRID) * CP_THREAD + tid;
        #pragma unroll 1
        for (int k = 0; k < 4; ++k) {     // 16 of 17 rounds, 4-deep ILP
            const unsigned i0 = i, i1 = i + CP_STRIDE,
                           i2 = i + 2 * CP_STRIDE, i3 = i + 3 * CP_STRIDE;
            const f4 a0 = __builtin_nontemporal_load(src + i0);
            const f4 a1 = __builtin_nontemporal_load(src + i1);
            const f4 a2 = __builtin_nontemporal_load(src + i2);
            const f4 a3 = __builtin_nontemporal_load(src + i3);
            __builtin_nontemporal_store(a0, dst + i0 + (i0 / (unsigned)SLAB4) * SC4);
            __builtin_nontemporal_store(a1, dst + i1 + (i1 / (unsigned)SLAB4) * SC4);
            __builtin_nontemporal_store(a2, dst + i2 + (i2 / (unsigned)SLAB4) * SC4);
            __builtin_nontemporal_store(a3, dst + i3 + (i3 / (unsigned)SLAB4) * SC4);
            i += 4 * CP_STRIDE;
        }
        {                                 // round 17
            const f4 a = __builtin_nontemporal_load(src + i);
            __builtin_nontemporal_store(a, dst + i + (i / (unsigned)SLAB4) * SC4);
            i += CP_STRIDE;
        }
        if (i < (unsigned)CP_N4) {        // partial tail round
            const f4 a = __builtin_nontemporal_load(src + i);
            __builtin_nontemporal_store(a, dst + i + (i / (unsigned)SLAB4) * SC4);
        }
        return;
    }

    // ---- proj ----
    const int ent0 = bid * 32;

    for (int i = tid; i < (DIN * DSC) / 4; i += 256)
        ((f4*)Ws)[i] = ((const f4*)Wp)[i];
    __syncthreads();

    const int g   = tid >> 3;             // entity within block
    const int dq  = (tid & 7) * 4;        // first of 4 output channels
    const int ent = ent0 + g;

    const f4* __restrict__ erow = (const f4*)(emb + (size_t)ent * DIN);

    float ax = bp[dq + 0], ay = bp[dq + 1], az = bp[dq + 2], aw = bp[dq + 3];

    #pragma unroll 4
    for (int k4 = 0; k4 < DIN / 4; ++k4) {
        const f4 ev = erow[k4];
        const int k = k4 * 4;
        const f4 w0 = *(const f4*)&Ws[k + 0][dq];
        const f4 w1 = *(const f4*)&Ws[k + 1][dq];
        const f4 w2 = *(const f4*)&Ws[k + 2][dq];
        const f4 w3 = *(const f4*)&Ws[k + 3][dq];
        ax = fmaf(ev.x, w0.x, fmaf(ev.y, w1.x, fmaf(ev.z, w2.x, fmaf(ev.w, w3.x, ax))));
        ay = fmaf(ev.x, w0.y, fmaf(ev.y, w1.y, fmaf(ev.z, w2.y, fmaf(ev.w, w3.y, ay))));
        az = fmaf(ev.x, w0.z, fmaf(ev.y, w1.z, fmaf(ev.z, w2.z, fmaf(ev.w, w3.z, az))));
        aw = fmaf(ev.x, w0.w, fmaf(ev.y, w1.w, fmaf(ev.z, w2.w, fmaf(ev.w, w3.w, aw))));
    }

    const float m = mask[ent];
    f4 r;
    r.x = fmaxf(ax, 0.f) * m;
    r.y = fmaxf(ay, 0.f) * m;
    r.z = fmaxf(az, 0.f) * m;
    r.w = fmaxf(aw, 0.f) * m;
    ((f4*)projws)[(size_t)ent * (DSC / 4) + (tid & 7)] = r;

    if ((tid & 7) == 0) {
        int y = loc[2 * ent + 0];
        int x = loc[2 * ent + 1];
        y = min(max(y, 0), Hh - 1);
        x = min(max(x, 0), Ww - 1);
        idxws[ent] = y * Ww + x;
    }
}

// ---------------------------------------------------------------------------
// Kernel B: gather. Block = (b, scatter-channel c, half-plane). Zero a
// 48.6 KB LDS accumulator, scan the batch's 512 entity cells (2/thread),
// LDS-atomicAdd in-range contributions (proj from L2-resident projws; zero
// values skipped — exact), then dump as one contiguous NT stream. Blocks
// ordered by dst address.
// ---------------------------------------------------------------------------
__global__ __launch_bounds__(256) void gather_kernel(
    const float* __restrict__ projws, const int* __restrict__ idxws,
    float* __restrict__ out) {

    __shared__ float facc[HALF];          // 48,640 B

    const int g    = blockIdx.x;          // 0 .. Bsz*DSC*2-1, dst-address order
    const int b    = g >> 6;
    const int c    = (g >> 1) & 31;
    const int lo   = (g & 1) * HALF;
    const int tid  = threadIdx.x;

    for (int i = tid; i < HP4; i += 256) ((f4*)facc)[i] = (f4)(0.f);
    __syncthreads();

    const int2 v = ((const int2*)(idxws + b * Nn))[tid];  // entities 2t, 2t+1
    {
        const int r0 = v.x - lo;
        if ((unsigned)r0 < (unsigned)HALF) {
            const float p = projws[((size_t)b * Nn + 2 * tid) * DSC + c];
            if (p != 0.f) atomicAdd(&facc[r0], p);
        }
        const int r1 = v.y - lo;
        if ((unsigned)r1 < (unsigned)HALF) {
            const float p = projws[((size_t)b * Nn + 2 * tid + 1) * DSC + c];
            if (p != 0.f) atomicAdd(&facc[r1], p);
        }
    }
    __syncthreads();

    f4* obase = (f4*)(out + ((size_t)(b * COUT + Cc + c)) * HW + lo);
    for (int i = tid; i < HP4; i += 256)
        __builtin_nontemporal_store(((const f4*)facc)[i], obase + i);
}

// ---------------------------------------------------------------------------
// Fallback path (only if ws_size too small): R1 design.
// ---------------------------------------------------------------------------
__global__ __launch_bounds__(256) void init_out_kernel(
    const float* __restrict__ spatial, float* __restrict__ out) {
    const int plane = blockIdx.x;
    const int b = plane / COUT;
    const int c = plane % COUT;
    f4* dst = (f4*)(out + (size_t)plane * HW);
    if (c < Cc) {
        const f4* src = (const f4*)(spatial + ((size_t)b * Cc + c) * HW);
        for (int i = threadIdx.x; i < HW / 4; i += blockDim.x) dst[i] = src[i];
    } else {
        for (int i = threadIdx.x; i < HW / 4; i += blockDim.x) dst[i] = (f4)(0.f);
    }
}

__global__ __launch_bounds__(256) void scatter_kernel(
    const float* __restrict__ emb, const float* __restrict__ mask,
    const int* __restrict__ loc, const float* __restrict__ Wp,
    const float* __restrict__ bp, float* __restrict__ out) {

    __shared__ float Ws[DIN][DSC];
    __shared__ float Es[32][DIN + 4];

    const int tid  = threadIdx.x;
    const int ent0 = blockIdx.x * 32;

    for (int i = tid; i < (DIN * DSC) / 4; i += 256)
        ((f4*)Ws)[i] = ((const f4*)Wp)[i];
    for (int i = tid; i < (32 * DIN) / 4; i += 256) {
        const int e  = i >> 6;
        const int k4 = i & 63;
        *(f4*)&Es[e][k4 * 4] =
            ((const f4*)(emb + (size_t)(ent0 + e) * DIN))[k4];
    }
    __syncthreads();

    const int g   = tid >> 3;
    const int dq  = (tid & 7) * 4;
    const int ent = ent0 + g;
    const int b   = ent >> 9;

    float ax = bp[dq + 0], ay = bp[dq + 1], az = bp[dq + 2], aw = bp[dq + 3];

    #pragma unroll 4
    for (int k = 0; k < DIN; k += 4) {
        const f4 ev = *(const f4*)&Es[g][k];
        const f4 w0 = *(const f4*)&Ws[k + 0][dq];
        const f4 w1 = *(const f4*)&Ws[k + 1][dq];
        const f4 w2 = *(const f4*)&Ws[k + 2][dq];
        const f4 w3 = *(const f4*)&Ws[k + 3][dq];
        ax = fmaf(ev.x, w0.x, fmaf(ev.y, w1.x, fmaf(ev.z, w2.x, fmaf(ev.w, w3.x, ax))));
        ay = fmaf(ev.x, w0.y, fmaf(ev.y, w1.y, fmaf(ev.z, w2.y, fmaf(ev.w, w3.y, ay))));
        az = fmaf(ev.x, w0.z, fmaf(ev.y, w1.z, fmaf(ev.z, w2.z, fmaf(ev.w, w3.z, az))));
        aw = fmaf(ev.x, w0.w, fmaf(ev.y, w1.w, fmaf(ev.z, w2.w, fmaf(ev.w, w3.w, aw))));
    }

    const float m = mask[ent];
    int y = loc[2 * ent + 0];
    int x = loc[2 * ent + 1];
    y = min(max(y, 0), Hh - 1);
    x = min(max(x, 0), Ww - 1);

    float* dst = out + ((size_t)b * COUT + Cc) * HW + (size_t)y * Ww + x;
    float v[4] = { ax, ay, az, aw };
    #pragma unroll
    for (int j = 0; j < 4; ++j) {
        const float r = fmaxf(v[j], 0.f) * m;
        if (r != 0.f)
            atomicAdd(dst + (size_t)(dq + j) * HW, r);
    }
}

// ---------------------------------------------------------------------------
extern "C" void kernel_launch(void* const* d_in, const int* in_sizes, int n_in,
                              void* d_out, int out_size, void* d_ws, size_t ws_size,
                              hipStream_t stream) {
    const float* spatial = (const float*)d_in[0];  // [B, C, H, W]
    const float* emb     = (const float*)d_in[1];  // [B, N, DIN]
    const float* mask    = (const float*)d_in[2];  // [B, N]
    const int*   loc     = (const int*)d_in[3];    // [B, N, 2]
    const float* Wp      = (const float*)d_in[4];  // [DIN, DSC]
    const float* bp      = (const float*)d_in[5];  // [DSC]
    float* out = (float*)d_out;                    // [B, COUT, H, W]

    const size_t need = (size_t)Bsz * Nn * DSC * sizeof(float)
                      + (size_t)Bsz * Nn * sizeof(int);
    if (ws_size >= need) {
        float* projws = (float*)d_ws;
        int*   idxws  = (int*)((char*)d_ws + (size_t)Bsz * Nn * DSC * sizeof(float));
        proj_copy_kernel<<<PR_GRID + CP_GRID, CP_THREAD, 0, stream>>>(
            spatial, emb, mask, loc, Wp, bp, out, projws, idxws);
        gather_kernel<<<Bsz * DSC * 2, 256, 0, stream>>>(projws, idxws, out);
    } else {
        init_out_kernel<<<Bsz * COUT, 256, 0, stream>>>(spatial, out);
        scatter_kernel<<<(Bsz * Nn) / 32, 256, 0, stream>>>(emb, mask, loc, Wp, bp, out);
    }
}

// Round 9
// 71.439 us; speedup vs baseline: 1.4808x; 1.1239x over previous
//
#include <hip/hip_runtime.h>

// Problem constants (from reference)
#define Bsz  32
#define Nn   512
#define DIN  256
#define DSC  32
#define Cc   48
#define Hh   152
#define Ww   160
#define HW   (Hh * Ww)        // 24320
#define COUT (Cc + DSC)       // 80
#define HALF (HW / 2)         // 12160 cells per half-plane
#define HP4  (HALF / 4)       // 3040 float4 per half-plane

// Copy geometry: linear over spatial (one contiguous 149 MB stream).
#define CP_N4     (Bsz * Cc * (HW / 4))   // 9,338,880 float4 to copy
#define CP_GRID   2048
#define CP_THREAD 256
#define CP_STRIDE (CP_GRID * CP_THREAD)   // 524,288 f4 = 8 MB sliding window
#define SLAB4     (Cc * (HW / 4))         // 291,840 f4 per batch copy-slab
#define SC4       ((COUT - Cc) * (HW / 4))// 194,560 f4 dst slab shift per batch
#define PR_GRID   ((Bsz * Nn) / 32)       // 512 proj blocks

// Native clang vector type — required by __builtin_nontemporal_*.
typedef float f4 __attribute__((ext_vector_type(4)));

// ---------------------------------------------------------------------------
// Kernel A: proj + copy fused. Proj blocks first (bid 0..511).
//  Copy: CACHED loads (spatial is 149 MB < 256 MB L3 -> stays resident
//  across graph replays; reads served from Infinity Cache) + NT stores
//  (write stream does not allocate/evict L3). 4-deep batched per wave.
// ---------------------------------------------------------------------------
__global__ __launch_bounds__(CP_THREAD, 4) void proj_copy_kernel(
    const float* __restrict__ spatial, const float* __restrict__ emb,
    const float* __restrict__ mask, const int* __restrict__ loc,
    const float* __restrict__ Wp, const float* __restrict__ bp,
    float* __restrict__ out, float* __restrict__ projws,
    int* __restrict__ idxws) {

    __shared__ float Ws[DIN][DSC];        // 32 KB (proj blocks only)

    const int bid = blockIdx.x;
    const int tid = threadIdx.x;

    if (bid >= PR_GRID) {                 // ---- sliding-window copy ----
        const f4* __restrict__ src = (const f4*)spatial;
        f4* __restrict__       dst = (f4*)out;
        unsigned i = (bid - PR_GRID) * CP_THREAD + tid;
        #pragma unroll 1
        for (int k = 0; k < 4; ++k) {     // 16 of 17 rounds, 4-deep ILP
            const unsigned i0 = i, i1 = i + CP_STRIDE,
                           i2 = i + 2 * CP_STRIDE, i3 = i + 3 * CP_STRIDE;
            const f4 a0 = src[i0];        // cached: L3-resident after replay 1
            const f4 a1 = src[i1];
            const f4 a2 = src[i2];
            const f4 a3 = src[i3];
            __builtin_nontemporal_store(a0, dst + i0 + (i0 / (unsigned)SLAB4) * SC4);
            __builtin_nontemporal_store(a1, dst + i1 + (i1 / (unsigned)SLAB4) * SC4);
            __builtin_nontemporal_store(a2, dst + i2 + (i2 / (unsigned)SLAB4) * SC4);
            __builtin_nontemporal_store(a3, dst + i3 + (i3 / (unsigned)SLAB4) * SC4);
            i += 4 * CP_STRIDE;
        }
        {                                 // round 17
            const f4 a = src[i];
            __builtin_nontemporal_store(a, dst + i + (i / (unsigned)SLAB4) * SC4);
            i += CP_STRIDE;
        }
        if (i < (unsigned)CP_N4) {        // partial tail round
            const f4 a = src[i];
            __builtin_nontemporal_store(a, dst + i + (i / (unsigned)SLAB4) * SC4);
        }
        return;
    }

    // ---- proj ----
    const int ent0 = bid * 32;

    for (int i = tid; i < (DIN * DSC) / 4; i += 256)
        ((f4*)Ws)[i] = ((const f4*)Wp)[i];
    __syncthreads();

    const int g   = tid >> 3;             // entity within block
    const int dq  = (tid & 7) * 4;        // first of 4 output channels
    const int ent = ent0 + g;

    const f4* __restrict__ erow = (const f4*)(emb + (size_t)ent * DIN);

    float ax = bp[dq + 0], ay = bp[dq + 1], az = bp[dq + 2], aw = bp[dq + 3];

    #pragma unroll 4
    for (int k4 = 0; k4 < DIN / 4; ++k4) {
        const f4 ev = erow[k4];
        const int k = k4 * 4;
        const f4 w0 = *(const f4*)&Ws[k + 0][dq];
        const f4 w1 = *(const f4*)&Ws[k + 1][dq];
        const f4 w2 = *(const f4*)&Ws[k + 2][dq];
        const f4 w3 = *(const f4*)&Ws[k + 3][dq];
        ax = fmaf(ev.x, w0.x, fmaf(ev.y, w1.x, fmaf(ev.z, w2.x, fmaf(ev.w, w3.x, ax))));
        ay = fmaf(ev.x, w0.y, fmaf(ev.y, w1.y, fmaf(ev.z, w2.y, fmaf(ev.w, w3.y, ay))));
        az = fmaf(ev.x, w0.z, fmaf(ev.y, w1.z, fmaf(ev.z, w2.z, fmaf(ev.w, w3.z, az))));
        aw = fmaf(ev.x, w0.w, fmaf(ev.y, w1.w, fmaf(ev.z, w2.w, fmaf(ev.w, w3.w, aw))));
    }

    const float m = mask[ent];
    f4 r;
    r.x = fmaxf(ax, 0.f) * m;
    r.y = fmaxf(ay, 0.f) * m;
    r.z = fmaxf(az, 0.f) * m;
    r.w = fmaxf(aw, 0.f) * m;
    ((f4*)projws)[(size_t)ent * (DSC / 4) + (tid & 7)] = r;

    if ((tid & 7) == 0) {
        int y = loc[2 * ent + 0];
        int x = loc[2 * ent + 1];
        y = min(max(y, 0), Hh - 1);
        x = min(max(x, 0), Ww - 1);
        idxws[ent] = y * Ww + x;
    }
}

// ---------------------------------------------------------------------------
// Kernel B: gather. Block = (b, scatter-channel c, half-plane). Zero a
// 48.6 KB LDS accumulator, scan the batch's 512 entity cells (2/thread),
// LDS-atomicAdd in-range contributions (zero values skipped — exact), then
// dump as one contiguous NT stream. Blocks ordered by dst address.
// ---------------------------------------------------------------------------
__global__ __launch_bounds__(256) void gather_kernel(
    const float* __restrict__ projws, const int* __restrict__ idxws,
    float* __restrict__ out) {

    __shared__ float facc[HALF];          // 48,640 B

    const int g    = blockIdx.x;          // 0 .. Bsz*DSC*2-1, dst-address order
    const int b    = g >> 6;
    const int c    = (g >> 1) & 31;
    const int lo   = (g & 1) * HALF;
    const int tid  = threadIdx.x;

    for (int i = tid; i < HP4; i += 256) ((f4*)facc)[i] = (f4)(0.f);
    __syncthreads();

    const int2 v = ((const int2*)(idxws + b * Nn))[tid];  // entities 2t, 2t+1
    {
        const int r0 = v.x - lo;
        if ((unsigned)r0 < (unsigned)HALF) {
            const float p = projws[((size_t)b * Nn + 2 * tid) * DSC + c];
            if (p != 0.f) atomicAdd(&facc[r0], p);
        }
        const int r1 = v.y - lo;
        if ((unsigned)r1 < (unsigned)HALF) {
            const float p = projws[((size_t)b * Nn + 2 * tid + 1) * DSC + c];
            if (p != 0.f) atomicAdd(&facc[r1], p);
        }
    }
    __syncthreads();

    f4* obase = (f4*)(out + ((size_t)(b * COUT + Cc + c)) * HW + lo);
    for (int i = tid; i < HP4; i += 256)
        __builtin_nontemporal_store(((const f4*)facc)[i], obase + i);
}

// ---------------------------------------------------------------------------
// Fallback path (only if ws_size too small): R1 design.
// ---------------------------------------------------------------------------
__global__ __launch_bounds__(256) void init_out_kernel(
    const float* __restrict__ spatial, float* __restrict__ out) {
    const int plane = blockIdx.x;
    const int b = plane / COUT;
    const int c = plane % COUT;
    f4* dst = (f4*)(out + (size_t)plane * HW);
    if (c < Cc) {
        const f4* src = (const f4*)(spatial + ((size_t)b * Cc + c) * HW);
        for (int i = threadIdx.x; i < HW / 4; i += blockDim.x) dst[i] = src[i];
    } else {
        for (int i = threadIdx.x; i < HW / 4; i += blockDim.x) dst[i] = (f4)(0.f);
    }
}

__global__ __launch_bounds__(256) void scatter_kernel(
    const float* __restrict__ emb, const float* __restrict__ mask,
    const int* __restrict__ loc, const float* __restrict__ Wp,
    const float* __restrict__ bp, float* __restrict__ out) {

    __shared__ float Ws[DIN][DSC];
    __shared__ float Es[32][DIN + 4];

    const int tid  = threadIdx.x;
    const int ent0 = blockIdx.x * 32;

    for (int i = tid; i < (DIN * DSC) / 4; i += 256)
        ((f4*)Ws)[i] = ((const f4*)Wp)[i];
    for (int i = tid; i < (32 * DIN) / 4; i += 256) {
        const int e  = i >> 6;
        const int k4 = i & 63;
        *(f4*)&Es[e][k4 * 4] =
            ((const f4*)(emb + (size_t)(ent0 + e) * DIN))[k4];
    }
    __syncthreads();

    const int g   = tid >> 3;
    const int dq  = (tid & 7) * 4;
    const int ent = ent0 + g;
    const int b   = ent >> 9;

    float ax = bp[dq + 0], ay = bp[dq + 1], az = bp[dq + 2], aw = bp[dq + 3];

    #pragma unroll 4
    for (int k = 0; k < DIN; k += 4) {
        const f4 ev = *(const f4*)&Es[g][k];
        const f4 w0 = *(const f4*)&Ws[k + 0][dq];
        const f4 w1 = *(const f4*)&Ws[k + 1][dq];
        const f4 w2 = *(const f4*)&Ws[k + 2][dq];
        const f4 w3 = *(const f4*)&Ws[k + 3][dq];
        ax = fmaf(ev.x, w0.x, fmaf(ev.y, w1.x, fmaf(ev.z, w2.x, fmaf(ev.w, w3.x, ax))));
        ay = fmaf(ev.x, w0.y, fmaf(ev.y, w1.y, fmaf(ev.z, w2.y, fmaf(ev.w, w3.y, ay))));
        az = fmaf(ev.x, w0.z, fmaf(ev.y, w1.z, fmaf(ev.z, w2.z, fmaf(ev.w, w3.z, az))));
        aw = fmaf(ev.x, w0.w, fmaf(ev.y, w1.w, fmaf(ev.z, w2.w, fmaf(ev.w, w3.w, aw))));
    }

    const float m = mask[ent];
    int y = loc[2 * ent + 0];
    int x = loc[2 * ent + 1];
    y = min(max(y, 0), Hh - 1);
    x = min(max(x, 0), Ww - 1);

    float* dst = out + ((size_t)b * COUT + Cc) * HW + (size_t)y * Ww + x;
    float v[4] = { ax, ay, az, aw };
    #pragma unroll
    for (int j = 0; j < 4; ++j) {
        const float r = fmaxf(v[j], 0.f) * m;
        if (r != 0.f)
            atomicAdd(dst + (size_t)(dq + j) * HW, r);
    }
}

// ---------------------------------------------------------------------------
extern "C" void kernel_launch(void* const* d_in, const int* in_sizes, int n_in,
                              void* d_out, int out_size, void* d_ws, size_t ws_size,
                              hipStream_t stream) {
    const float* spatial = (const float*)d_in[0];  // [B, C, H, W]
    const float* emb     = (const float*)d_in[1];  // [B, N, DIN]
    const float* mask    = (const float*)d_in[2];  // [B, N]
    const int*   loc     = (const int*)d_in[3];    // [B, N, 2]
    const float* Wp      = (const float*)d_in[4];  // [DIN, DSC]
    const float* bp      = (const float*)d_in[5];  // [DSC]
    float* out = (float*)d_out;                    // [B, COUT, H, W]

    const size_t need = (size_t)Bsz * Nn * DSC * sizeof(float)
                      + (size_t)Bsz * Nn * sizeof(int);
    if (ws_size >= need) {
        float* projws = (float*)d_ws;
        int*   idxws  = (int*)((char*)d_ws + (size_t)Bsz * Nn * DSC * sizeof(float));
        proj_copy_kernel<<<PR_GRID + CP_GRID, CP_THREAD, 0, stream>>>(
            spatial, emb, mask, loc, Wp, bp, out, projws, idxws);
        gather_kernel<<<Bsz * DSC * 2, 256, 0, stream>>>(projws, idxws, out);
    } else {
        init_out_kernel<<<Bsz * COUT, 256, 0, stream>>>(spatial, out);
        scatter_kernel<<<(Bsz * Nn) / 32, 256, 0, stream>>>(emb, mask, loc, Wp, bp, out);
    }
}